// Round 1
// 212.782 us; speedup vs baseline: 1.0261x; 1.0261x over previous
//
#include <hip/hip_runtime.h>
#include <cstdint>
#include <cstddef>

typedef __attribute__((ext_vector_type(8))) __bf16 bf16x8;
typedef __attribute__((ext_vector_type(4))) float f32x4;

union bf8pack { unsigned short u[8]; bf16x8 v; uint4 q; };

// Fixed bucket capacity: bucket = 32 dst nodes, mean 512 edges, sigma~22.6.
// 768 = mean + 11 sigma -> overflow probability ~1e-29.
#define BCAP 768

static __device__ __forceinline__ unsigned short f2b(float f) {
    union { float f; unsigned int u; } v; v.f = f;
    unsigned int u = v.u;
    unsigned int r = (u + 0x7fffu + ((u >> 16) & 1u)) >> 16;  // RNE
    return (unsigned short)r;
}

// convert 8 consecutive fp32 -> bf16x8 (RNE)
static __device__ __forceinline__ bf16x8 cvt8(const float* __restrict__ p) {
    float4 f0 = *(const float4*)p;
    float4 f1 = *(const float4*)(p + 4);
    bf8pack pk;
    pk.u[0] = f2b(f0.x); pk.u[1] = f2b(f0.y);
    pk.u[2] = f2b(f0.z); pk.u[3] = f2b(f0.w);
    pk.u[4] = f2b(f1.x); pk.u[5] = f2b(f1.y);
    pk.u[6] = f2b(f1.z); pk.u[7] = f2b(f1.w);
    return pk.v;
}

// ---------------------------------------------------------------------------
// mega0: one dispatch, three independent jobs by block range.
//   blocks [0,256)    : edge scatter (R6-proven two-level chunk reservation)
//   blocks [256,768)  : k1  y = relu(x @ Wp^T + bp)  (Wp converted INLINE —
//                       removes the Wp_b ordering dependency that forced k1
//                       into its own dispatch; A-side was already inline)
//   blocks [768,1040) : weight convert Wcat/W1_b/W2_b (consumed only by the
//                       LATER pool/k45 dispatches — stream-ordered, no race)
// ---------------------------------------------------------------------------
__global__ __launch_bounds__(256) void mega0(
    const int* __restrict__ src, const int* __restrict__ dst,
    int* __restrict__ bcnt, unsigned int* __restrict__ pairs,
    const float* __restrict__ x, const float* __restrict__ Wp,
    const float* __restrict__ bp,
    const float* __restrict__ Ws, const float* __restrict__ Wn,
    const float* __restrict__ W1, const float* __restrict__ W2,
    unsigned short* __restrict__ Wcat, unsigned short* __restrict__ W1_b,
    unsigned short* __restrict__ W2_b, unsigned short* __restrict__ y)
{
    const int tid = threadIdx.x;
    const int bx = (int)blockIdx.x;

    if (bx >= 768) {            // ---- weight convert (tail blocks) ----
        int i = (bx - 768) * 256 + tid;
        if (i < 32768) {
            int o = i >> 8, k = i & 255;
            Wcat[i] = f2b(k < 128 ? Ws[o * 128 + k] : Wn[o * 128 + (k - 128)]);
        } else if (i < 65536) {
            W1_b[i - 32768] = f2b(W1[i - 32768]);
        } else {                // i < 69632
            W2_b[i - 65536] = f2b(W2[i - 65536]);
        }
        return;
    }

    if (bx >= 256) {            // ---- k1: y = relu(x @ Wp^T + bp) ----
        const int bm = bx - 256;
        const int w  = tid >> 6;
        const int wm = w & 1, wn = w >> 1;
        const int l  = tid & 63;
        const int lr = l & 15, quad = l >> 4;
        const int m0 = bm * 128 + wm * 64;
        const int n0 = wn * 64;

        f32x4 acc[4][4];
#pragma unroll
        for (int i = 0; i < 4; i++)
#pragma unroll
            for (int j = 0; j < 4; j++) acc[i][j] = (f32x4){0.f, 0.f, 0.f, 0.f};

        const float* Apf = x  + (size_t)(m0 + lr) * 128 + quad * 8;
        const float* Bpf = Wp + (size_t)(n0 + lr) * 128 + quad * 8;

#pragma unroll
        for (int ks = 0; ks < 4; ks++) {
            bf16x8 af[4], bf[4];
#pragma unroll
            for (int i = 0; i < 4; i++)
                af[i] = cvt8(Apf + (size_t)i * 16 * 128 + ks * 32);
#pragma unroll
            for (int i = 0; i < 4; i++)
                bf[i] = cvt8(Bpf + (size_t)i * 16 * 128 + ks * 32);
#pragma unroll
            for (int mi = 0; mi < 4; mi++)
#pragma unroll
                for (int ni = 0; ni < 4; ni++)
                    acc[mi][ni] = __builtin_amdgcn_mfma_f32_16x16x32_bf16(
                        af[mi], bf[ni], acc[mi][ni], 0, 0, 0);
        }

#pragma unroll
        for (int ni = 0; ni < 4; ni++) {
            const int col = n0 + ni * 16 + lr;
            const float bv = bp[col];
#pragma unroll
            for (int mi = 0; mi < 4; mi++) {
#pragma unroll
                for (int r = 0; r < 4; r++) {
                    const int row = m0 + mi * 16 + quad * 4 + r;
                    float v = acc[mi][ni][r] + bv;
                    v = v > 0.f ? v : 0.f;
                    y[(size_t)row * 128 + col] = f2b(v);
                }
            }
        }
        return;
    }

    // ---- scatter (blocks 0..255) ----
    __shared__ int h[2048];
    __shared__ int base_l[2048];
    __shared__ int cnt[2048];
    for (int i = tid; i < 2048; i += 256) { h[i] = 0; cnt[i] = 0; }
    __syncthreads();
    const int base = bx * 4096;
    int d_r[16], s_r[16];
    const int4* s4 = (const int4*)(src + base);
    const int4* d4 = (const int4*)(dst + base);
#pragma unroll
    for (int i = 0; i < 4; i++) {
        int4 dv = d4[tid + i * 256];
        int4 sv = s4[tid + i * 256];
        d_r[i * 4 + 0] = dv.x; d_r[i * 4 + 1] = dv.y;
        d_r[i * 4 + 2] = dv.z; d_r[i * 4 + 3] = dv.w;
        s_r[i * 4 + 0] = sv.x; s_r[i * 4 + 1] = sv.y;
        s_r[i * 4 + 2] = sv.z; s_r[i * 4 + 3] = sv.w;
    }
#pragma unroll
    for (int i = 0; i < 16; i++)
        atomicAdd(&h[((unsigned)d_r[i]) >> 5], 1);
    __syncthreads();
    for (int i = tid; i < 2048; i += 256)
        base_l[i] = h[i] ? (i * BCAP + atomicAdd(&bcnt[i], h[i])) : 0;
    __syncthreads();
#pragma unroll
    for (int i = 0; i < 16; i++) {
        int b = ((unsigned)d_r[i]) >> 5;
        int pos = base_l[b] + atomicAdd(&cnt[b], 1);
        if (pos < (b + 1) * BCAP)   // inert guard (overflow impossible at +11 sigma)
            pairs[pos] = ((unsigned)s_r[i] << 5) | ((unsigned)d_r[i] & 31u);
    }
}

// ---------------------------------------------------------------------------
// bucket_pool3 (R6-proven structure, unchanged except output -> dedicated
// pooled[N,128] bf16): block = bucket of 32 dst nodes; counting-sort pairs
// by dst into LDS, each wave owns 8 nodes, 8-deep clamped gather batches,
// register fmax.
// ---------------------------------------------------------------------------
__global__ __launch_bounds__(256) void bucket_pool3(
    const unsigned int* __restrict__ yu, const int* __restrict__ bcnt,
    const unsigned int* __restrict__ pairs, unsigned short* __restrict__ pooled)
{
    __shared__ unsigned short ldsSrc[1024];
    __shared__ int bin[32], offl[32], cnt2[32];
    const int b = blockIdx.x;
    const int tid = threadIdx.x;
    if (tid < 32) { bin[tid] = 0; cnt2[tid] = 0; }
    __syncthreads();
    const int beg = b * BCAP;
    int nb = bcnt[b]; nb = nb < BCAP ? nb : BCAP;

    for (int i = tid; i < nb; i += 256)
        atomicAdd(&bin[pairs[beg + i] & 31u], 1);
    __syncthreads();
    if (tid == 0) {
        int run = 0;
        for (int i = 0; i < 32; i++) { offl[i] = run; run += bin[i]; }
    }
    __syncthreads();
    for (int i = tid; i < nb; i += 256) {
        unsigned int p = pairs[beg + i];
        int d = p & 31u;
        int slot = offl[d] + atomicAdd(&cnt2[d], 1);
        ldsSrc[slot] = (unsigned short)(p >> 5);
    }
    __syncthreads();

    const int w = tid >> 6, lane = tid & 63;
    for (int ni = 0; ni < 8; ni++) {
        const int n = w * 8 + ni;
        const int e0 = offl[n], cnt = bin[n];
        float ax = 0.f, ay = 0.f;
        for (int e = 0; e < cnt; e += 8) {
            int s[8]; unsigned int v[8];
#pragma unroll
            for (int j = 0; j < 8; j++) {
                int idx = e + j; idx = idx < cnt ? idx : cnt - 1;   // clamp: dup last
                s[j] = ldsSrc[e0 + idx];
            }
#pragma unroll
            for (int j = 0; j < 8; j++) v[j] = yu[(size_t)s[j] * 64 + lane];
#pragma unroll
            for (int j = 0; j < 8; j++) {
                ax = fmaxf(ax, __uint_as_float(v[j] << 16));
                ay = fmaxf(ay, __uint_as_float(v[j] & 0xffff0000u));
            }
        }
        unsigned int packed = (__float_as_uint(ax) >> 16) | (__float_as_uint(ay) & 0xffff0000u);
        ((unsigned int*)pooled)[(size_t)(b * 32 + n) * 64 + lane] = packed;
    }
}

// ---------------------------------------------------------------------------
// k45: fused k4 + k5. Block = 64 rows.
//   phase A: h = leaky(concat(bf16(x), pooled) @ Wcat^T + bn) -> LDS Hs[64][136]
//            (xb recomputed inline from x — removes the bufX roundtrip;
//             pooled read from its dedicated buffer)
//   phase B: h2 = leaky(h @ W1^T + b1) -> LDS H2[64][264] (k5-proven, verbatim
//            except A comes from Hs instead of global hbuf)
//   head   : out = sigmoid(h2 @ W2^T + b2)
// LDS: 17.4K + 33.8K = 51.2 KB -> 3 blocks/CU.
// ---------------------------------------------------------------------------
__global__ __launch_bounds__(256) void k45(
    const float* __restrict__ x, const unsigned short* __restrict__ pooled,
    const unsigned short* __restrict__ Wcat, const float* __restrict__ bn,
    const unsigned short* __restrict__ W1_b, const float* __restrict__ b1,
    const unsigned short* __restrict__ W2_b, const float* __restrict__ b2,
    float* __restrict__ out)
{
    __shared__ unsigned short Hs[64 * 136];
    __shared__ unsigned short H2[64 * 264];
    const int tid = threadIdx.x;
    const int w = tid >> 6, l = tid & 63;
    const int lr = l & 15, quad = l >> 4;
    const int wm = w & 1, wn = w >> 1;
    const int row0 = blockIdx.x * 64;

    // ---- phase A: per wave 32 rows x 64 cols ----
    {
        f32x4 acc[2][4];
#pragma unroll
        for (int i = 0; i < 2; i++)
#pragma unroll
            for (int j = 0; j < 4; j++) acc[i][j] = (f32x4){0.f, 0.f, 0.f, 0.f};

        const float* Axp = x + (size_t)(row0 + wm * 32 + lr) * 128 + quad * 8;
        const unsigned short* App = pooled + (size_t)(row0 + wm * 32 + lr) * 128 + quad * 8;
        const unsigned short* Bp = Wcat + (size_t)(wn * 64 + lr) * 256 + quad * 8;

#pragma unroll
        for (int ks = 0; ks < 8; ks++) {
            bf16x8 af[2], bf[4];
            if (ks < 4) {       // k 0..127: A = bf16(x), B cols = Ws part
#pragma unroll
                for (int i = 0; i < 2; i++)
                    af[i] = cvt8(Axp + (size_t)i * 16 * 128 + ks * 32);
            } else {            // k 128..255: A = pooled, B cols = Wn part
#pragma unroll
                for (int i = 0; i < 2; i++)
                    af[i] = *(const bf16x8*)(App + (size_t)i * 16 * 128 + (ks - 4) * 32);
            }
#pragma unroll
            for (int i = 0; i < 4; i++)
                bf[i] = *(const bf16x8*)(Bp + (size_t)i * 16 * 256 + ks * 32);
#pragma unroll
            for (int mi = 0; mi < 2; mi++)
#pragma unroll
                for (int ni = 0; ni < 4; ni++)
                    acc[mi][ni] = __builtin_amdgcn_mfma_f32_16x16x32_bf16(
                        af[mi], bf[ni], acc[mi][ni], 0, 0, 0);
        }

#pragma unroll
        for (int ni = 0; ni < 4; ni++) {
            const int col = wn * 64 + ni * 16 + lr;
            const float bv = bn[col];
#pragma unroll
            for (int mi = 0; mi < 2; mi++) {
#pragma unroll
                for (int r = 0; r < 4; r++) {
                    const int row = wm * 32 + mi * 16 + quad * 4 + r;   // local
                    float v = acc[mi][ni][r] + bv;
                    v = v > 0.f ? v : 0.01f * v;
                    Hs[row * 136 + col] = f2b(v);
                }
            }
        }
    }
    __syncthreads();

    // ---- phase B: h2 = leaky(h @ W1^T + b1); per wave 32 rows x 128 cols ----
    {
        f32x4 acc[2][8];
#pragma unroll
        for (int i = 0; i < 2; i++)
#pragma unroll
            for (int j = 0; j < 8; j++) acc[i][j] = (f32x4){0.f, 0.f, 0.f, 0.f};

        const unsigned short* Bp = W1_b + (size_t)(wn * 128 + lr) * 128 + quad * 8;

#pragma unroll
        for (int ks = 0; ks < 4; ks++) {
            bf16x8 af[2], bfr[8];
#pragma unroll
            for (int i = 0; i < 2; i++)
                af[i] = *(const bf16x8*)&Hs[(wm * 32 + i * 16 + lr) * 136 + ks * 32 + quad * 8];
#pragma unroll
            for (int i = 0; i < 8; i++)
                bfr[i] = *(const bf16x8*)(Bp + (size_t)i * 16 * 128 + ks * 32);
#pragma unroll
            for (int mi = 0; mi < 2; mi++)
#pragma unroll
                for (int ni = 0; ni < 8; ni++)
                    acc[mi][ni] = __builtin_amdgcn_mfma_f32_16x16x32_bf16(
                        af[mi], bfr[ni], acc[mi][ni], 0, 0, 0);
        }

#pragma unroll
        for (int ni = 0; ni < 8; ni++) {
            const int col = wn * 128 + ni * 16 + lr;
            const float bv = b1[col];
#pragma unroll
            for (int mi = 0; mi < 2; mi++) {
#pragma unroll
                for (int r = 0; r < 4; r++) {
                    const int row = wm * 32 + mi * 16 + quad * 4 + r;   // local
                    float v = acc[mi][ni][r] + bv;
                    v = v > 0.f ? v : 0.01f * v;
                    H2[row * 264 + col] = f2b(v);
                }
            }
        }
    }
    __syncthreads();

    // ---- head: out = sigmoid(h2 @ W2^T + b2) ----
    const int m0 = w * 16;
    f32x4 a2 = (f32x4){0.f, 0.f, 0.f, 0.f};
#pragma unroll
    for (int ks = 0; ks < 8; ks++) {
        bf16x8 a = *(const bf16x8*)&H2[(m0 + lr) * 264 + ks * 32 + quad * 8];
        bf16x8 bb = *(const bf16x8*)(W2_b + (size_t)lr * 256 + ks * 32 + quad * 8);
        a2 = __builtin_amdgcn_mfma_f32_16x16x32_bf16(a, bb, a2, 0, 0, 0);
    }
    const float bv = b2[lr];
#pragma unroll
    for (int r = 0; r < 4; r++) {
        const int row = row0 + m0 + quad * 4 + r;
        float v = a2[r] + bv;
        out[(size_t)row * 16 + lr] = 1.f / (1.f + __expf(-v));
    }
}

// ---------------------------------------------------------------------------
extern "C" void kernel_launch(void* const* d_in, const int* in_sizes, int n_in,
                              void* d_out, int out_size, void* d_ws, size_t ws_size,
                              hipStream_t stream)
{
    const float* x  = (const float*)d_in[0];
    const float* Wp = (const float*)d_in[1];
    const float* bp = (const float*)d_in[2];
    const float* Ws = (const float*)d_in[3];
    const float* Wn = (const float*)d_in[4];
    const float* bn = (const float*)d_in[5];
    const float* W1 = (const float*)d_in[6];
    const float* b1 = (const float*)d_in[7];
    const float* W2 = (const float*)d_in[8];
    const float* b2 = (const float*)d_in[9];
    const int* src  = (const int*)d_in[10];
    const int* dst  = (const int*)d_in[11];
    float* out = (float*)d_out;

    const int N = in_sizes[0] / 128;   // 65536

    // ws layout:
    //   [ 0,16M)  y      : [N,128] bf16
    //   [16M,32M) pooled : [N,128] bf16
    //   [32M,..)  Wcat (128x256 bf16), W1_b (256x128), W2_b (16x256),
    //             bcnt (2048 ints), pairs (2048*BCAP uints ~6.3MB)
    unsigned short* y      = (unsigned short*)d_ws;
    unsigned short* pooled = (unsigned short*)((char*)d_ws + (size_t)16 * 1024 * 1024);
    unsigned short* Wcat   = (unsigned short*)((char*)d_ws + (size_t)32 * 1024 * 1024);
    unsigned short* W1_b = Wcat + 32768;
    unsigned short* W2_b = W1_b + 32768;
    int* bcnt = (int*)(W2_b + 4096);
    unsigned int* pairs = (unsigned int*)(bcnt + 2048);

    dim3 blk(256);

    hipMemsetAsync(bcnt, 0, 2048 * sizeof(int), stream);

    // scatter (256) | k1 (512) | weight convert (272) — independent jobs,
    // one dispatch; converted weights consumed only by later dispatches.
    mega0<<<1040, blk, 0, stream>>>(src, dst, bcnt, pairs,
                                    x, Wp, bp, Ws, Wn, W1, W2,
                                    Wcat, W1_b, W2_b, y);

    // pool: pooled = segment_max(y[src]) by dst
    bucket_pool3<<<2048, blk, 0, stream>>>((const unsigned int*)y, bcnt, pairs, pooled);

    // fused k4+k5: h, h2 live in LDS only
    k45<<<N / 64, blk, 0, stream>>>(x, pooled, Wcat, bn, W1_b, b1, W2_b, b2, out);
}